// Round 6
// baseline (379.766 us; speedup 1.0000x reference)
//
#include <hip/hip_runtime.h>
#include <stdint.h>
#include <stddef.h>

// ---------------- common helpers ----------------

typedef __bf16 bf16x8 __attribute__((ext_vector_type(8)));
typedef float  f32x4  __attribute__((ext_vector_type(4)));

#define MFMA16x16(a,b,c) __builtin_amdgcn_mfma_f32_16x16x32_bf16((a),(b),(c),0,0,0)

__device__ __forceinline__ uint16_t f2bf(float f){
  union { float f; uint32_t u; } v; v.f = f;
  uint32_t u = v.u + 0x7fffu + ((v.u >> 16) & 1u);
  return (uint16_t)(u >> 16);
}
__device__ __forceinline__ bf16x8 load_frag(const uint16_t* p){
  uint4 u = *reinterpret_cast<const uint4*>(p);
  return __builtin_bit_cast(bf16x8, u);
}
__device__ __forceinline__ f32x4 fzero(){
  f32x4 z = {0.f, 0.f, 0.f, 0.f};
  return z;
}
__device__ __forceinline__ uint32_t pack2(float a, float b){
  return (uint32_t)f2bf(a) | ((uint32_t)f2bf(b) << 16);
}
// async global->LDS DMA, 16B per lane, LDS dst = wave-uniform base + lane*16
__device__ __forceinline__ void gl2lds16(const uint16_t* g, uint16_t* l){
  __builtin_amdgcn_global_load_lds(
      (const __attribute__((address_space(1))) uint32_t*)g,
      (__attribute__((address_space(3))) uint32_t*)l,
      16, 0, 0);
}

// ---------------- 1) merged transpose + f32->bf16 convert (3 mats) ---------
__global__ __launch_bounds__(256) void k_transpose_all(const float* __restrict__ w_up,
                                                       const float* __restrict__ w_o,
                                                       const float* __restrict__ w_down,
                                                       uint16_t* __restrict__ w_up_t,
                                                       uint16_t* __restrict__ w_o_t,
                                                       uint16_t* __restrict__ w_dn_t){
  __shared__ float t[32][33];
  int id = blockIdx.x;
  const float* in; uint16_t* out; int R, C, bx, by;
  if(id < 1728){ in = w_up;  out = w_up_t; R = 192;  C = 9216; bx = id % 288; by = id / 288; }
  else if(id < 4800){ id -= 1728; in = w_o; out = w_o_t; R = 3072; C = 1024; bx = id % 32; by = id / 32; }
  else { id -= 4800; in = w_down; out = w_dn_t; R = 1024; C = 192; bx = id % 6; by = id / 6; }
  const int tc = bx * 32, tr = by * 32;
  const int j = threadIdx.x & 31, i0 = threadIdx.x >> 5;
  for(int ii = 0; ii < 4; ++ii){
    int r = i0 + ii * 8;
    t[r][j] = in[(size_t)(tr + r) * C + tc + j];
  }
  __syncthreads();
  for(int ii = 0; ii < 4; ++ii){
    int c = i0 + ii * 8;
    out[(size_t)(tc + c) * R + tr + j] = f2bf(t[j][c]);
  }
}

// ---------------- 2) down-proj + RMSNorm via MFMA ----------------
__global__ __launch_bounds__(256) void k_down_mfma(const float* __restrict__ x,
                                                   const uint16_t* __restrict__ wdt,
                                                   const float* __restrict__ rms_w,
                                                   uint16_t* __restrict__ h_out){
  __shared__ __align__(16) uint16_t as[32 * 64];
  __shared__ float hsq[32];
  const int tid  = threadIdx.x;
  const int wave = tid >> 6, lane = tid & 63;
  const int ml = lane & 15, qd = lane >> 4;
  const int m0 = blockIdx.x * 32;
  const int n0w = wave * 48;
  if(tid < 32) hsq[tid] = 0.f;

  f32x4 acc[2][3];
#pragma unroll
  for(int mt = 0; mt < 2; ++mt)
#pragma unroll
    for(int nt = 0; nt < 3; ++nt) acc[mt][nt] = fzero();

  const int srow = tid >> 3, sc = tid & 7;
  for(int kt = 0; kt < 16; ++kt){
    const float* src = x + (size_t)(m0 + srow) * 1024 + kt * 64 + sc * 8;
    float4 a = *reinterpret_cast<const float4*>(src);
    float4 b = *reinterpret_cast<const float4*>(src + 4);
    uint4 pk;
    pk.x = pack2(a.x, a.y); pk.y = pack2(a.z, a.w);
    pk.z = pack2(b.x, b.y); pk.w = pack2(b.z, b.w);
    __syncthreads();
    *reinterpret_cast<uint4*>(as + srow * 64 + ((sc ^ (srow & 7)) * 8)) = pk;
    __syncthreads();
#pragma unroll
    for(int kk = 0; kk < 2; ++kk){
      bf16x8 af[2];
#pragma unroll
      for(int mt = 0; mt < 2; ++mt){
        int row = mt * 16 + ml;
        af[mt] = load_frag(as + row * 64 + (((kk * 4 + qd) ^ (row & 7)) * 8));
      }
#pragma unroll
      for(int nt = 0; nt < 3; ++nt){
        bf16x8 bfr = load_frag(wdt + (size_t)(n0w + nt * 16 + ml) * 1024 + kt * 64 + kk * 32 + qd * 8);
#pragma unroll
        for(int mt = 0; mt < 2; ++mt)
          acc[mt][nt] = MFMA16x16(af[mt], bfr, acc[mt][nt]);
      }
    }
  }
  __syncthreads();
#pragma unroll
  for(int mt = 0; mt < 2; ++mt)
#pragma unroll
    for(int r = 0; r < 4; ++r){
      float s = acc[mt][0][r]*acc[mt][0][r] + acc[mt][1][r]*acc[mt][1][r] + acc[mt][2][r]*acc[mt][2][r];
#pragma unroll
      for(int off = 1; off < 16; off <<= 1) s += __shfl_xor(s, off);
      if(ml == 0) atomicAdd(&hsq[mt * 16 + qd * 4 + r], s);
    }
  __syncthreads();
  float rw[3];
#pragma unroll
  for(int nt = 0; nt < 3; ++nt) rw[nt] = rms_w[n0w + nt * 16 + ml];
#pragma unroll
  for(int mt = 0; mt < 2; ++mt)
#pragma unroll
    for(int r = 0; r < 4; ++r){
      int row = mt * 16 + qd * 4 + r;
      float scl = rsqrtf(hsq[row] * (1.0f / 192.0f) + 1e-6f);
#pragma unroll
      for(int nt = 0; nt < 3; ++nt)
        h_out[(size_t)(m0 + row) * 192 + n0w + nt * 16 + ml] = f2bf(acc[mt][nt][r] * scl * rw[nt]);
    }
}

// ---------------- 3) up-proj GEMM: LDS repack -> full-line stores ----------
__global__ __launch_bounds__(256) void k_gemm_up(const uint16_t* __restrict__ hmat,
                                                 const uint16_t* __restrict__ wt,
                                                 uint16_t* __restrict__ q_t,
                                                 uint16_t* __restrict__ k_t,
                                                 uint16_t* __restrict__ v_t){
  __shared__ __align__(16) uint16_t rp[16 * 129 * 8];   // 33,024 B
  const int wave = threadIdx.x >> 6, lane = threadIdx.x & 63;
  const int ml = lane & 15, qd = lane >> 4;
  const int m0 = blockIdx.y * 32;
  const int bx = blockIdx.x;
  const int which = bx / 6;                // 0=q 1=k 2=v
  const int d0b = (bx % 6) * 32;
  const int n0w = bx * 512 + wave * 128;
  const int d0w = d0b + wave * 8;

  bf16x8 af[2][6];
#pragma unroll
  for(int mt = 0; mt < 2; ++mt)
#pragma unroll
    for(int kk = 0; kk < 6; ++kk)
      af[mt][kk] = load_frag(hmat + (size_t)(m0 + mt * 16 + ml) * 192 + kk * 32 + qd * 8);

  f32x4 acc[8][2];
#pragma unroll
  for(int nt = 0; nt < 8; ++nt){ acc[nt][0] = fzero(); acc[nt][1] = fzero(); }
#pragma unroll
  for(int nt = 0; nt < 8; ++nt){
#pragma unroll
    for(int kk = 0; kk < 6; ++kk){
      bf16x8 b = load_frag(wt + (size_t)(n0w + nt * 16 + ml) * 192 + kk * 32 + qd * 8);
      acc[nt][0] = MFMA16x16(af[0][kk], b, acc[nt][0]);
      acc[nt][1] = MFMA16x16(af[1][kk], b, acc[nt][1]);
    }
  }

  const int b   = m0 >> 11;
  const int s0  = m0 & 2047;
  const int kt2 = s0 >> 6;
  const int row0 = s0 & 63;
  uint4* rp4 = (uint4*)rp;

  if(which < 2){
    const float qs = which ? 1.0f : 0.07216878364870322f;   // fold 1/sqrt(192) into Q
    const bool rope = (d0w >= 128) && (d0w < 160);
#pragma unroll
    for(int mt = 0; mt < 2; ++mt)
#pragma unroll
      for(int r = 0; r < 4; ++r){
        int t = mt * 16 + qd * 4 + r;
        int s = s0 + t;
        float v[8];
#pragma unroll
        for(int nt = 0; nt < 8; ++nt) v[nt] = acc[nt][mt][r] * qs;
        if(rope){
#pragma unroll
          for(int pi = 0; pi < 4; ++pi){
            int fi = (d0w + 2 * pi - 128) >> 1;
            float invf = __expf(-(float)fi * 0.5756462732485114f); // ln(10000)/16
            float sn, cs;
            sincosf((float)s * invf, &sn, &cs);
            float e = v[2 * pi], o = v[2 * pi + 1];
            v[2 * pi]     = e * cs - o * sn;
            v[2 * pi + 1] = o * cs + e * sn;
          }
        }
        uint4 pk;
        pk.x = pack2(v[0], v[1]); pk.y = pack2(v[2], v[3]);
        pk.z = pack2(v[4], v[5]); pk.w = pack2(v[6], v[7]);
        rp4[ml * 129 + t * 4 + (wave ^ (t & 3))] = pk;
      }
  } else {
#pragma unroll
    for(int nt = 0; nt < 8; ++nt){
      int dl = wave * 8 + nt;
#pragma unroll
      for(int mt = 0; mt < 2; ++mt){
        int jc = mt * 2 + (qd >> 1);
        int slot = ml * 129 + dl * 4 + (jc ^ (dl & 3));
        uint2 pk;
        pk.x = pack2(acc[nt][mt][0], acc[nt][mt][1]);
        pk.y = pack2(acc[nt][mt][2], acc[nt][mt][3]);
        *(reinterpret_cast<uint2*>(rp + slot * 8) + (qd & 1)) = pk;
      }
    }
  }
  __syncthreads();

  if(which < 2){
    uint16_t* dst = which ? k_t : q_t;
    const int cb = d0b >> 3;
#pragma unroll
    for(int it = 0; it < 8; ++it){
      int h = wave * 4 + (it & 3), rhalf = it >> 2;
      int tloc = rhalf * 16 + (lane >> 2), p = lane & 3;
      int row = row0 + tloc;
      uint4 val = rp4[h * 129 + tloc * 4 + p];
      size_t off = ((size_t)(b * 16 + h) * 32 + kt2) * 12288
                 + (size_t)row * 192 + ((cb ^ (tloc & 4)) + p) * 8;
      *reinterpret_cast<uint4*>(dst + off) = val;
    }
  } else {
    const int cs0 = row0 >> 3;
#pragma unroll
    for(int it = 0; it < 8; ++it){
      int h = wave * 4 + (it & 3), dhalf = it >> 2;
      int dl = dhalf * 16 + (lane >> 2), p = lane & 3;
      uint4 val = rp4[h * 129 + dl * 4 + p];
      size_t off = ((size_t)(b * 16 + h) * 32 + kt2) * 12288
                 + (size_t)(d0b + dl) * 64 + ((cs0 ^ (dl & 4)) + p) * 8;
      *reinterpret_cast<uint4*>(v_t + off) = val;
    }
  }
}

// ---------------- 4) causal flash attention, Q-tile 128 ----------------
// Grid 512 (2 blocks/CU).  Wave = 32 q-rows (2 groups of 16).  K-tile 64.
// LDS: ks 24KB | vs 26KB (+16 ones rows) | ps 16KB (dedicated, wave-private)
// = 66KB -> 2 blocks/CU.  2 barriers per K-tile (P write->read is same-wave).
// Last K-tile: lower-half waves fully masked -> wave-uniform skip.
__global__ __launch_bounds__(256, 2) void k_attn(const uint16_t* __restrict__ q_t,
                                                 const uint16_t* __restrict__ k_t,
                                                 const uint16_t* __restrict__ v_t,
                                                 uint16_t* __restrict__ attn_out){
  __shared__ __align__(16) uint16_t lds[33792];   // 67,584 B
  uint16_t* ks = lds;                // 12288 elems: K tile [64][192] swizzled
  uint16_t* vs = lds + 12288;        // 13312 elems: V^T [192+16][64] swizzled
  uint16_t* ps = lds + 25600;        // 8192 elems: P, 4 waves x [32][64]
  const int tid  = threadIdx.x;
  const int wave = tid >> 6;
  const int lane = tid & 63;
  const int ml   = lane & 15;
  const int qd   = lane >> 4;
  const int L    = blockIdx.x;
  const int idx  = L >> 3;
  const int qt2  = 15 - (idx & 15);              // heavy q-tiles first per XCD
  const int bh   = (L & 7) + ((idx >> 4) << 3);  // 4 heads per XCD
  const int q0   = qt2 * 128;
  const int last = 2 * qt2 + 1;

  // ones rows (192..207) of V -> row-sum column of o
  {
    uint32_t* vw = (uint32_t*)(lds + 24576);
    vw[tid] = 0x3F803F80u;
    vw[tid + 256] = 0x3F803F80u;
  }
  // stage Q (two consecutive 64-row tiles) into ks||vs region
  {
    const uint16_t* qsrc = q_t + ((size_t)bh * 32 + 2 * qt2) * 12288;
#pragma unroll
    for(int it = 0; it < 12; ++it){
      int seg = it * 4 + wave;
      gl2lds16(qsrc + seg * 512 + lane * 8, lds + seg * 512);
    }
  }
  __syncthreads();
  bf16x8 qf[2][6];
#pragma unroll
  for(int mg = 0; mg < 2; ++mg){
    int row = wave * 32 + mg * 16 + ml;
    int t64 = row >> 6, rl = row & 63;
#pragma unroll
    for(int kk = 0; kk < 6; ++kk)
      qf[mg][kk] = load_frag(lds + t64 * 12288 + rl * 192 + (((kk * 4 + qd) ^ (rl & 7)) * 8));
  }

  f32x4 o[2][13];
#pragma unroll
  for(int mg = 0; mg < 2; ++mg)
#pragma unroll
    for(int i = 0; i < 13; ++i) o[mg][i] = fzero();

  for(int kt = 0; kt <= last; ++kt){
    __syncthreads();                             // prior QK (ks) + PV (vs) reads done
    const uint16_t* ktile = k_t + ((size_t)bh * 32 + kt) * 12288;
    const uint16_t* vtile = v_t + ((size_t)bh * 32 + kt) * 12288;
#pragma unroll
    for(int it = 0; it < 6; ++it){
      int seg = it * 4 + wave;
      gl2lds16(ktile + seg * 512 + lane * 8, ks + seg * 512);
      gl2lds16(vtile + seg * 512 + lane * 8, vs + seg * 512);
    }
    __syncthreads();                             // DMA drained

    const bool full_skip = (kt == last) && (wave < 2);
    if(!full_skip){
      const bool need_mask = (wave < 2) ? (kt == last - 1) : (kt == last);
#pragma unroll
      for(int mg = 0; mg < 2; ++mg){
        float p[4][4];
#pragma unroll
        for(int nt = 0; nt < 4; ++nt){
          f32x4 a = fzero();
          int row = nt * 16 + ml;
#pragma unroll
          for(int kk = 0; kk < 6; ++kk){
            bf16x8 bfr = load_frag(ks + row * 192 + (((kk * 4 + qd) ^ (row & 7)) * 8));
            a = MFMA16x16(qf[mg][kk], bfr, a);
          }
#pragma unroll
          for(int r = 0; r < 4; ++r){
            float e = __expf(a[r]);
            if(need_mask){
              int i = q0 + wave * 32 + mg * 16 + qd * 4 + r;
              int j = kt * 64 + nt * 16 + ml;
              if(j > i) e = 0.f;
            }
            p[nt][r] = e;
          }
        }
        uint16_t* psw = ps + wave * 2048 + mg * 1024;
#pragma unroll
        for(int nt = 0; nt < 4; ++nt)
#pragma unroll
          for(int r = 0; r < 4; ++r){
            int rp2 = qd * 4 + r;
            int col = nt * 16 + ml;
            int c = (col >> 3) ^ (rp2 & 7);
            psw[rp2 * 64 + c * 8 + (col & 7)] = f2bf(p[nt][r]);
          }
      }
      // O += P V  (shared V frags feed both row-groups)
#pragma unroll
      for(int kk2 = 0; kk2 < 2; ++kk2){
        int cp = (kk2 * 4 + qd) ^ (ml & 7);
        bf16x8 pa0 = load_frag(ps + wave * 2048 + ml * 64 + cp * 8);
        bf16x8 pa1 = load_frag(ps + wave * 2048 + 1024 + ml * 64 + cp * 8);
#pragma unroll
        for(int dt = 0; dt < 13; ++dt){
          int row = dt * 16 + ml;
          int cv = (kk2 * 4 + qd) ^ (row & 7);
          bf16x8 vb = load_frag(vs + row * 64 + cv * 8);
          o[0][dt] = MFMA16x16(pa0, vb, o[0][dt]);
          o[1][dt] = MFMA16x16(pa1, vb, o[1][dt]);
        }
      }
    }
  }

  const int hh = bh & 15, b = bh >> 4;
#pragma unroll
  for(int mg = 0; mg < 2; ++mg)
#pragma unroll
    for(int r = 0; r < 4; ++r){
      int i = q0 + wave * 32 + mg * 16 + qd * 4 + r;
      float inv = 1.0f / o[mg][12][r];
      size_t obase = ((size_t)b * 2048 + i) * 3072 + hh * 192;
#pragma unroll
      for(int dt = 0; dt < 12; ++dt)
        attn_out[obase + dt * 16 + ml] = f2bf(o[mg][dt][r] * inv);
    }
}

// ---------------- 5) out-proj GEMM: m97-style LDS-tiled, split-K=2 ----------
__global__ __launch_bounds__(256) void k_gemm_o_tile(const uint16_t* __restrict__ a,
                                                     const uint16_t* __restrict__ wt,
                                                     float* __restrict__ part){
  __shared__ __align__(16) uint16_t as[128 * 64];
  __shared__ __align__(16) uint16_t bs[128 * 64];
  const int wave = threadIdx.x >> 6, lane = threadIdx.x & 63;
  const int ml = lane & 15, qd = lane >> 4;
  const int m0 = blockIdx.y * 128, n0 = blockIdx.x * 128;
  const int kz = blockIdx.z;
  const int mo = (wave >> 1) * 64, no = (wave & 1) * 64;

  const int lrow = lane >> 3;
  const int gch  = (lane & 7) ^ (lrow & 7);
  const uint16_t* abase = a  + (size_t)(m0 + lrow) * 3072 + kz * 1536 + gch * 8;
  const uint16_t* bbase = wt + (size_t)(n0 + lrow) * 3072 + kz * 1536 + gch * 8;

  f32x4 acc[4][4];
#pragma unroll
  for(int mt = 0; mt < 4; ++mt)
#pragma unroll
    for(int nt = 0; nt < 4; ++nt) acc[mt][nt] = fzero();

  for(int kt = 0; kt < 24; ++kt){
    __syncthreads();
#pragma unroll
    for(int it = 0; it < 4; ++it){
      int seg = it * 4 + wave;
      gl2lds16(abase + (size_t)seg * 24576 + kt * 64, as + seg * 512);
      gl2lds16(bbase + (size_t)seg * 24576 + kt * 64, bs + seg * 512);
    }
    __syncthreads();
#pragma unroll
    for(int ks2 = 0; ks2 < 2; ++ks2){
      bf16x8 af[4], bfr[4];
#pragma unroll
      for(int mt = 0; mt < 4; ++mt){
        int row = mo + mt * 16 + ml;
        af[mt] = load_frag(as + row * 64 + (((ks2 * 4 + qd) ^ (row & 7)) * 8));
      }
#pragma unroll
      for(int nt = 0; nt < 4; ++nt){
        int row = no + nt * 16 + ml;
        bfr[nt] = load_frag(bs + row * 64 + (((ks2 * 4 + qd) ^ (row & 7)) * 8));
      }
#pragma unroll
      for(int mt = 0; mt < 4; ++mt)
#pragma unroll
        for(int nt = 0; nt < 4; ++nt)
          acc[mt][nt] = MFMA16x16(af[mt], bfr[nt], acc[mt][nt]);
    }
  }

  float* dst = part + (size_t)kz * 4096 * 1024;
#pragma unroll
  for(int mt = 0; mt < 4; ++mt)
#pragma unroll
    for(int nt = 0; nt < 4; ++nt)
#pragma unroll
      for(int r = 0; r < 4; ++r){
        int row = m0 + mo + mt * 16 + qd * 4 + r;
        int col = n0 + no + nt * 16 + ml;
        dst[(size_t)row * 1024 + col] = acc[mt][nt][r];
      }
}

// out = part0 + part1 (float4)
__global__ __launch_bounds__(256) void k_addout(const float* __restrict__ part,
                                                float* __restrict__ out){
  int i = blockIdx.x * 256 + threadIdx.x;
  const float4* p0 = (const float4*)part;
  const float4* p1 = p0 + (size_t)1048576;
  float4 a = p0[i], b = p1[i];
  float4 c; c.x = a.x + b.x; c.y = a.y + b.y; c.z = a.z + b.z; c.w = a.w + b.w;
  ((float4*)out)[i] = c;
}

// ---------------- launch ----------------

extern "C" void kernel_launch(void* const* d_in, const int* in_sizes, int n_in,
                              void* d_out, int out_size, void* d_ws, size_t ws_size,
                              hipStream_t stream) {
  (void)in_sizes; (void)n_in; (void)out_size; (void)ws_size;
  const float* x      = (const float*)d_in[0];
  const float* w_down = (const float*)d_in[2];
  const float* rms_w  = (const float*)d_in[3];
  const float* w_up   = (const float*)d_in[4];
  const float* w_o    = (const float*)d_in[5];
  float* out = (float*)d_out;

  char* ws = (char*)d_ws;
  uint16_t* h_bf   = (uint16_t*)(ws);                     // 1,572,864 B
  uint16_t* w_up_t = (uint16_t*)(ws + 1572864);           // 3,538,944 B
  uint16_t* w_o_t  = (uint16_t*)(ws + 5111808);           // 6,291,456 B
  uint16_t* w_dn_t = (uint16_t*)(ws + 11403264);          //   393,216 B
  uint16_t* q_tb   = (uint16_t*)(ws + 11796480);          // 25,165,824 B
  uint16_t* k_tb   = (uint16_t*)(ws + 36962304);          // 25,165,824 B
  uint16_t* v_tb   = (uint16_t*)(ws + 62128128);          // 25,165,824 B
  uint16_t* attnO  = (uint16_t*)(ws + 87293952);          // 25,165,824 B
  float*    part   = (float*)(ws + 11796480);             // alias q_tb/k_tb (dead after attn)

  k_transpose_all<<<4992, 256, 0, stream>>>(w_up, w_o, w_down, w_up_t, w_o_t, w_dn_t);
  k_down_mfma<<<128, 256, 0, stream>>>(x, w_dn_t, rms_w, h_bf);
  k_gemm_up<<<dim3(18, 128), 256, 0, stream>>>(h_bf, w_up_t, q_tb, k_tb, v_tb);
  k_attn<<<512, 256, 0, stream>>>(q_tb, k_tb, v_tb, attnO);
  k_gemm_o_tile<<<dim3(8, 32, 2), 256, 0, stream>>>(attnO, w_o_t, part);
  k_addout<<<4096, 256, 0, stream>>>(part, out);
}